// Round 17
// baseline (910.521 us; speedup 1.0000x reference)
//
#include <hip/hip_runtime.h>
#include <hip/hip_bf16.h>

#define T_STEPS 365
#define XLEN    (T_STEPS * 3)
#define H_SZ    256
#define ROWS    4      // batch rows per block (256 blocks, 1 per CU)
#define NBLK    256
#define NW      4      // waves per block (1 per SIMD -> 512-reg unified budget)
#define CPW     64     // state cols per wave

#define SF1     (-1.4426950408889634f)   // -log2(e): folded into W_f, W_o
#define SF2     (-2.8853900817779268f)   // -2 log2(e): folded into W_g, tanh(c)

typedef __attribute__((ext_vector_type(8))) short bf16x8;   // 8 bf16 = 4 VGPRs
typedef __attribute__((ext_vector_type(4))) short bf16x4;   // 4 bf16 = 2 VGPRs
typedef __attribute__((ext_vector_type(4))) float f32x4;

__device__ __forceinline__ float fast_sigmoid(float x) {    // plain form (iv only)
    return __builtin_amdgcn_rcpf(1.0f + __builtin_amdgcn_exp2f(-1.44269504f * x));
}
__device__ __forceinline__ unsigned short f2bf(float x) {   // fp32 -> bf16 RTNE
    __hip_bfloat16 b = __float2bfloat16(x);
    return *reinterpret_cast<unsigned short*>(&b);
}
__device__ __forceinline__ float bf2f(unsigned short v) {
    return __uint_as_float(((unsigned)v) << 16);
}

// Round-17: register-resident weights, 1 wave/SIMD.
// 4 waves x 64 cols; per wave: f,g all 8kt (64 frags, 256 regs -> AGPR) +
// o kt0-5 (24 frags, 96 regs); only o kt6,7 in LDS (32 KB). Removes the
// 128 wo-b128-reads/CU/step that dominated R16's LDS residual (~512 cyc).
// Gates: 2-stage xor4/xor8 redistribution -> 4 h-elems/lane
//   lane m: row = m&3, ct = ((m>>3)<<1)|((m>>2)&1)
// zx coefs f32 in LDS (48 KB), read per-gate in the gate phase (short live).
__global__ void __launch_bounds__(256, 1)
ealstm_fused(const float* __restrict__ x_dyn, const float* __restrict__ x_stat,
             const float* __restrict__ w_i, const float* __restrict__ b_i,
             const float* __restrict__ w_f, const float* __restrict__ b_f,
             const float* __restrict__ w_g, const float* __restrict__ b_g,
             const float* __restrict__ w_o, const float* __restrict__ b_o,
             const float* __restrict__ w_head, const float* __restrict__ b_head,
             float* __restrict__ out)
{
    const int tid   = threadIdx.x;
    const int lane  = tid & 63;
    const int wv    = tid >> 6;       // 0..3
    const int m     = lane & 15;      // B-operand row slot
    const int l16   = lane >> 4;      // 0..3
    const int rb    = blockIdx.x * ROWS;
    const int wbase = wv * CPW;

    const int r_eff  = m & 3;                              // batch row this lane GATES
    const int ct_eff = ((m >> 3) << 1) | ((m >> 2) & 1);   // ct tile this lane GATES

    __shared__ unsigned short wo_lds[4 * 2 * 256 * 8];    // 32 KB [l16][kt-6][c][e]
    __shared__ unsigned short hbuf[2][4096];              // 16 KB h^T B-pack, dbuf
    __shared__ f32x4          cof4[12 * 256];             // 48 KB zx coefs [(g*4+q)][tid]
    __shared__ float          red[NW][ROWS];

    const float* wsrc[3] = {w_f, w_g, w_o};
    const float* bsrc[3] = {b_f, b_g, b_o};
    const float  gsf[3]  = {SF1, SF2, SF1};

    // ---- one-time staging ----
    // o-gate Wh kt=6,7 -> LDS A-frags (pre-scaled)
    for (int idx = tid; idx < 4 * 2 * 8 * 256; idx += 256) {
        const int c    = idx & 255;
        const int e    = (idx >> 8) & 7;
        const int kt2  = (idx >> 11) & 1;
        const int l16g = idx >> 12;
        wo_lds[((l16g * 2 + kt2) * 256 + c) * 8 + e] =
            f2bf(SF1 * w_o[(3 + (kt2 + 6) * 32 + l16g * 8 + e) * H_SZ + c]);
    }
    // zx coef table: this lane's 12 {w0,w1,w2,b} vectors (pre-scaled, f32)
    {
        const int cw0 = wbase + ct_eff * 16 + l16 * 4;
#pragma unroll
        for (int g = 0; g < 3; ++g)
#pragma unroll
            for (int q = 0; q < 4; ++q) {
                const int c = cw0 + q;
                f32x4 v;
                v[0] = gsf[g] * wsrc[g][0 * H_SZ + c];
                v[1] = gsf[g] * wsrc[g][1 * H_SZ + c];
                v[2] = gsf[g] * wsrc[g][2 * H_SZ + c];
                v[3] = gsf[g] * bsrc[g][c];
                cof4[(g * 4 + q) * 256 + tid] = v;
            }
    }
    // zero BOTH h buffers (row slots >=4 must stay zero forever)
    for (int idx = tid; idx < 4096; idx += 256) ((unsigned int*)hbuf)[idx] = 0u;

    // ---- weights -> registers (pre-scaled) ----
    // A map (K=32): lane holds A[c = wbase+ct*16+(lane&15)][k' = l16*8+e]
    bf16x8 wFG[8][4][2];     // f,g gates, 8 kt x 4 ct = 64 frags (256 regs, AGPR)
    bf16x8 wO[6][4];         // o gate, kt 0..5 = 24 frags (96 regs)
#pragma unroll
    for (int ct = 0; ct < 4; ++ct) {
        const int c = wbase + ct * 16 + m;
#pragma unroll
        for (int g = 0; g < 2; ++g)
#pragma unroll
            for (int kt = 0; kt < 8; ++kt) {
                bf16x8 a;
#pragma unroll
                for (int e = 0; e < 8; ++e)
                    a[e] = (short)f2bf(gsf[g] * wsrc[g][(3 + kt * 32 + l16 * 8 + e) * H_SZ + c]);
                wFG[kt][ct][g] = a;
            }
#pragma unroll
        for (int kt = 0; kt < 6; ++kt) {
            bf16x8 a;
#pragma unroll
            for (int e = 0; e < 8; ++e)
                a[e] = (short)f2bf(SF1 * w_o[(3 + kt * 32 + l16 * 8 + e) * H_SZ + c]);
            wO[kt][ct] = a;
        }
    }

    // ---- static input gate + cell state (4 elements) ----
    const int cw0 = wbase + ct_eff * 16 + l16 * 4;
    float iv[4], cst[4];
    {
        const float xs0 = x_stat[(rb + r_eff) * 3 + 0];
        const float xs1 = x_stat[(rb + r_eff) * 3 + 1];
        const float xs2 = x_stat[(rb + r_eff) * 3 + 2];
#pragma unroll
        for (int q = 0; q < 4; ++q) {
            const int c = cw0 + q;
            iv[q] = fast_sigmoid(b_i[c] + xs0 * w_i[c] + xs1 * w_i[H_SZ + c]
                                        + xs2 * w_i[2 * H_SZ + c]);
            cst[q] = 0.0f;
        }
    }

    // h-write offset: cols cw0..cw0+3 (aligned quad), row r_eff -> B-pack slot
    const int woff = ((cw0 >> 5) * 64 + r_eff + 16 * ((cw0 & 31) >> 3)) * 8 + (cw0 & 7);

    // loop-invariant base pointers
    const float*  xr     = x_dyn + (size_t)(rb + r_eff) * XLEN;
    const bf16x8* wobase = (const bf16x8*)wo_lds;   // [l16][kt-6][c][e]

    __syncthreads();

    for (int t = 0; t < T_STEPS; ++t) {
        const int cur = t & 1;
        const bf16x8* hp = (const bf16x8*)hbuf[cur] + lane;
        unsigned short* hw = hbuf[cur ^ 1];

        // x for this lane's row (L1-resident)
        const float x0 = xr[t * 3 + 0];
        const float x1 = xr[t * 3 + 1];
        const float x2 = xr[t * 3 + 2];

        // o-gate kt6,7 A-frags (only LDS weight reads left: 8/wave/step)
        bf16x8 wot[2][4];
#pragma unroll
        for (int k2 = 0; k2 < 2; ++k2)
#pragma unroll
            for (int ct = 0; ct < 4; ++ct)
                wot[k2][ct] = wobase[(l16 * 2 + k2) * 256 + wbase + ct * 16 + m];

        // ---- z = h @ Wh : 96 MFMAs, 12 independent chains ----
        f32x4 acc[4][3];
        {
            const f32x4 z4 = {0.f, 0.f, 0.f, 0.f};
            const bf16x8 b0 = hp[0];
#pragma unroll
            for (int ct = 0; ct < 4; ++ct) {
                acc[ct][0] = __builtin_amdgcn_mfma_f32_16x16x32_bf16(wFG[0][ct][0], b0, z4, 0, 0, 0);
                acc[ct][1] = __builtin_amdgcn_mfma_f32_16x16x32_bf16(wFG[0][ct][1], b0, z4, 0, 0, 0);
                acc[ct][2] = __builtin_amdgcn_mfma_f32_16x16x32_bf16(wO[0][ct],     b0, z4, 0, 0, 0);
            }
        }
#pragma unroll
        for (int kt = 1; kt < 8; ++kt) {
            const bf16x8 b = hp[kt * 64];
#pragma unroll
            for (int ct = 0; ct < 4; ++ct) {
                const bf16x8 wo = (kt < 6) ? wO[kt][ct] : wot[kt - 6][ct];
                acc[ct][0] = __builtin_amdgcn_mfma_f32_16x16x32_bf16(wFG[kt][ct][0], b, acc[ct][0], 0, 0, 0);
                acc[ct][1] = __builtin_amdgcn_mfma_f32_16x16x32_bf16(wFG[kt][ct][1], b, acc[ct][1], 0, 0, 0);
                acc[ct][2] = __builtin_amdgcn_mfma_f32_16x16x32_bf16(wo,             b, acc[ct][2], 0, 0, 0);
            }
        }

        // ---- 2-stage gate redistribution (verified lane map) ----
        // stage 1 (xor 4): accQ[j] = (m&4) ? partner's acc[2j+1] : own acc[2j]
        float accQ[2][3][4];
#pragma unroll
        for (int j = 0; j < 2; ++j)
#pragma unroll
            for (int g = 0; g < 3; ++g)
#pragma unroll
                for (int q = 0; q < 4; ++q) {
                    const float s = __shfl_xor(acc[2 * j + 1][g][q], 4);
                    accQ[j][g][q] = (m & 4) ? s : acc[2 * j][g][q];
                }
        // stage 2 (xor 8): z = (m&8) ? partner's accQ[1] : own accQ[0]
        float z[3][4];
#pragma unroll
        for (int g = 0; g < 3; ++g)
#pragma unroll
            for (int q = 0; q < 4; ++q) {
                const float s = __shfl_xor(accQ[1][g][q], 8);
                z[g][q] = (m & 8) ? s : accQ[0][g][q];
            }

        // ---- z += x @ Wx + b (f32 coefs from LDS, short live range) ----
#pragma unroll
        for (int g = 0; g < 3; ++g)
#pragma unroll
            for (int q = 0; q < 4; ++q) {
                const f32x4 w = cof4[(g * 4 + q) * 256 + tid];
                z[g][q] += w[3] + x0 * w[0] + x1 * w[1] + x2 * w[2];
            }

        // ---- gates (fused-rcp: 4 exp2 + 2 rcp per element; 4 elems/lane) ----
        bf16x4 pk;
#pragma unroll
        for (int q = 0; q < 4; ++q) {
            const float Ef = __builtin_amdgcn_exp2f(z[0][q]);
            const float Eg = __builtin_amdgcn_exp2f(z[1][q]);
            const float Eo = __builtin_amdgcn_exp2f(z[2][q]);
            const float u  = 1.0f + Eg;
            const float v  = 1.0f + Ef;
            const float t2 = iv[q] * (2.0f - u);          // i*(1-Eg)
            const float cq = (cst[q] * u + t2 * v) * __builtin_amdgcn_rcpf(u * v);
            cst[q] = cq;
            const float Ec = __builtin_amdgcn_exp2f(SF2 * cq);
            const float hq = (1.0f - Ec) * __builtin_amdgcn_rcpf((1.0f + Eo) * (1.0f + Ec));
            pk[q] = (short)f2bf(hq);
        }
        *(bf16x4*)&hw[woff] = pk;
        __syncthreads();
    }

    // ---- head: out[r] = sum_c h[r][c] w_head[c] + b_head ----
    float p = 0.0f;
    {
        const unsigned short* hf = hbuf[1];   // t=364: cur=0, wrote hbuf[1]
        const f32x4 wh = *(const f32x4*)&w_head[cw0];
        const bf16x4 hv = *(const bf16x4*)&hf[woff];
#pragma unroll
        for (int q = 0; q < 4; ++q) p += bf2f((unsigned short)hv[q]) * wh[q];
    }
    p += __shfl_xor(p, 4);    // combine ct groups (same r_eff)
    p += __shfl_xor(p, 8);
    p += __shfl_xor(p, 16);   // combine l16 groups
    p += __shfl_xor(p, 32);
    if (lane < ROWS) red[wv][lane] = p;
    __syncthreads();
    if (tid < ROWS) {
        float s = b_head[0];
#pragma unroll
        for (int w = 0; w < NW; ++w) s += red[w][tid];
        out[rb + tid] = s;
    }
}

extern "C" void kernel_launch(void* const* d_in, const int* in_sizes, int n_in,
                              void* d_out, int out_size, void* d_ws, size_t ws_size,
                              hipStream_t stream)
{
    const float* x_dyn  = (const float*)d_in[0];
    const float* x_stat = (const float*)d_in[1];
    const float* w_i    = (const float*)d_in[2];
    const float* b_i    = (const float*)d_in[3];
    const float* w_f    = (const float*)d_in[4];
    const float* b_f    = (const float*)d_in[5];
    const float* w_g    = (const float*)d_in[6];
    const float* b_g    = (const float*)d_in[7];
    const float* w_o    = (const float*)d_in[8];
    const float* b_o    = (const float*)d_in[9];
    const float* w_head = (const float*)d_in[10];
    const float* b_head = (const float*)d_in[11];

    ealstm_fused<<<dim3(NBLK), dim3(256), 0, stream>>>(
        x_dyn, x_stat, w_i, b_i, w_f, b_f, w_g, b_g, w_o, b_o,
        w_head, b_head, (float*)d_out);
}

// Round 18
// 525.094 us; speedup vs baseline: 1.7340x; 1.7340x over previous
//
#include <hip/hip_runtime.h>
#include <hip/hip_bf16.h>

#define T_STEPS 365
#define XLEN    (T_STEPS * 3)
#define H_SZ    256
#define ROWS    4      // batch rows per block (256 blocks, 1 per CU)
#define NBLK    256
#define NW      8      // waves per block (2 per SIMD)
#define CPW     32     // state cols per wave

#define SF1     (-1.4426950408889634f)   // -log2(e): folded into W_f, W_o
#define SF2     (-2.8853900817779268f)   // -2 log2(e): folded into W_g, tanh(c)

typedef __attribute__((ext_vector_type(8))) short bf16x8;   // 8 bf16 = 4 VGPRs
typedef __attribute__((ext_vector_type(4))) short bf16x4;   // 4 bf16 = 2 VGPRs
typedef __attribute__((ext_vector_type(4))) float f32x4;

__device__ __forceinline__ float fast_sigmoid(float x) {    // plain form (iv only)
    return __builtin_amdgcn_rcpf(1.0f + __builtin_amdgcn_exp2f(-1.44269504f * x));
}
__device__ __forceinline__ unsigned short f2bf(float x) {   // fp32 -> bf16 RTNE
    __hip_bfloat16 b = __float2bfloat16(x);
    return *reinterpret_cast<unsigned short*>(&b);
}
__device__ __forceinline__ float bf2f(unsigned short v) {
    return __uint_as_float(((unsigned)v) << 16);
}

// Round-18 = exact revert to Round-16 (best: 523 us), per R17's pre-committed
// failure branch. R17 proved 1 wave/SIMD loses more to exposed latency than
// it saves in LDS reads; R16 is the measured optimum of this design space.
//   * ROWS=4, 256 blocks (all CUs). 2-stage gate redistribution:
//     lane m: row m&3, ct m>>3, q-pair (m>>2)&1 -> 2 gate elems/lane.
//   * z_x on VALU from 24 resident f32 coef regs; x straight from x_dyn (L1).
//   * pre-scaled weights (exp2-native fused-rcp gates), o-gate in LDS,
//     f,g in AGPRs, reg-prefetched per step.
__global__ void __launch_bounds__(512, 2)
ealstm_fused(const float* __restrict__ x_dyn, const float* __restrict__ x_stat,
             const float* __restrict__ w_i, const float* __restrict__ b_i,
             const float* __restrict__ w_f, const float* __restrict__ b_f,
             const float* __restrict__ w_g, const float* __restrict__ b_g,
             const float* __restrict__ w_o, const float* __restrict__ b_o,
             const float* __restrict__ w_head, const float* __restrict__ b_head,
             float* __restrict__ out)
{
    const int tid   = threadIdx.x;
    const int lane  = tid & 63;
    const int wv    = tid >> 6;       // 0..7
    const int m     = lane & 15;      // B-operand row slot
    const int l16   = lane >> 4;      // 0..3
    const int rb    = blockIdx.x * ROWS;
    const int wbase = wv * CPW;

    const int r_eff  = m & 3;         // batch row this lane GATES
    const int ct_eff = m >> 3;        // ct tile this lane GATES (stage A bit)
    const int qp     = ((m >> 2) & 1) * 2;   // q-pair base (stage B bit)

    __shared__ unsigned short wo_lds[4 * 8 * 256 * 8];    // 128 KB [l16][kt][c][e]
    __shared__ unsigned short hbuf[2][4096];              // 16 KB h^T B-pack, dbuf
    __shared__ float          red[NW][ROWS];

    // ---- one-time staging ----
    for (int idx = tid; idx < 4 * 8 * 8 * 256; idx += 512) {
        const int c    = idx & 255;
        const int e    = (idx >> 8) & 7;
        const int kt   = (idx >> 11) & 7;
        const int l16g = idx >> 14;
        wo_lds[((l16g * 8 + kt) * 256 + c) * 8 + e] =
            f2bf(SF1 * w_o[(3 + kt * 32 + l16g * 8 + e) * H_SZ + c]);
    }
    // zero BOTH h buffers: row slots (L&15)>=4 must stay zero forever
    for (int idx = tid; idx < 4096; idx += 512) ((unsigned int*)hbuf)[idx] = 0u;

    const float* wsrc[3] = {w_f, w_g, w_o};
    const float* bsrc[3] = {b_f, b_g, b_o};
    const float  gsf[3]  = {SF1, SF2, SF1};

    // ---- recurrent weights -> registers (pre-scaled); layout unchanged ----
    bf16x8 wA[8][2][2];      // f,g gates, all 8 kt = 128 regs (AGPR side)
#pragma unroll
    for (int ct = 0; ct < 2; ++ct) {
        const int c = wbase + ct * 16 + m;
#pragma unroll
        for (int g = 0; g < 2; ++g)
#pragma unroll
            for (int kt = 0; kt < 8; ++kt) {
                bf16x8 a;
#pragma unroll
                for (int e = 0; e < 8; ++e)
                    a[e] = (short)f2bf(gsf[g] * wsrc[g][(3 + kt * 32 + l16 * 8 + e) * H_SZ + c]);
                wA[kt][ct][g] = a;
            }
    }

    // ---- x/bias coefs for this lane's 2 gate elements (24 f32 regs) ----
    const int cw0 = wbase + ct_eff * 16 + l16 * 4 + qp;
    f32x4 cxw[2][3];    // [elem][gate] = {w0,w1,w2,b} pre-scaled
#pragma unroll
    for (int e = 0; e < 2; ++e)
#pragma unroll
        for (int g = 0; g < 3; ++g) {
            const int c = cw0 + e;
            f32x4 v;
            v[0] = gsf[g] * wsrc[g][0 * H_SZ + c];
            v[1] = gsf[g] * wsrc[g][1 * H_SZ + c];
            v[2] = gsf[g] * wsrc[g][2 * H_SZ + c];
            v[3] = gsf[g] * bsrc[g][c];
            cxw[e][g] = v;
        }

    // ---- static input gate + cell state (2 elements) ----
    float iv[2], cst[2];
    {
        const float xs0 = x_stat[(rb + r_eff) * 3 + 0];
        const float xs1 = x_stat[(rb + r_eff) * 3 + 1];
        const float xs2 = x_stat[(rb + r_eff) * 3 + 2];
#pragma unroll
        for (int e = 0; e < 2; ++e) {
            const int c = cw0 + e;
            iv[e] = fast_sigmoid(b_i[c] + xs0 * w_i[c] + xs1 * w_i[H_SZ + c]
                                        + xs2 * w_i[2 * H_SZ + c]);
            cst[e] = 0.0f;
        }
    }

    // h-write offset: col cw0 (even), row r_eff -> B-pack slot; ushort2 write
    const int kw  = cw0 >> 5;
    const int kp  = cw0 & 31;
    const int woff = ((kw * 64) + r_eff + 16 * (kp >> 3)) * 8 + (kp & 7);

    // loop-invariant base pointers
    const float*  xr     = x_dyn + (size_t)(rb + r_eff) * XLEN;
    const bf16x8* wobase = (const bf16x8*)&wo_lds[((l16 * 8) * 256 + wbase + m) * 8];

    __syncthreads();

    for (int t = 0; t < T_STEPS; ++t) {
        const int cur = t & 1;
        const bf16x8* hp = (const bf16x8*)hbuf[cur] + lane;
        unsigned short* hw = hbuf[cur ^ 1];

        // x for this lane's row (L1-resident, broadcast across 16 lanes)
        const float x0 = xr[t * 3 + 0];
        const float x1 = xr[t * 3 + 1];
        const float x2 = xr[t * 3 + 2];

        // ---- z = h @ Wh : 48 MFMAs/wave, kt0 inits from zero ----
        f32x4 acc[2][3];
        {
            const f32x4 z4 = {0.f, 0.f, 0.f, 0.f};
            const bf16x8 b0  = hp[0];
            const bf16x8 wo0 = wobase[0];
            const bf16x8 wo1 = wobase[16];
            acc[0][0] = __builtin_amdgcn_mfma_f32_16x16x32_bf16(wA[0][0][0], b0, z4, 0, 0, 0);
            acc[0][1] = __builtin_amdgcn_mfma_f32_16x16x32_bf16(wA[0][0][1], b0, z4, 0, 0, 0);
            acc[0][2] = __builtin_amdgcn_mfma_f32_16x16x32_bf16(wo0,         b0, z4, 0, 0, 0);
            acc[1][0] = __builtin_amdgcn_mfma_f32_16x16x32_bf16(wA[0][1][0], b0, z4, 0, 0, 0);
            acc[1][1] = __builtin_amdgcn_mfma_f32_16x16x32_bf16(wA[0][1][1], b0, z4, 0, 0, 0);
            acc[1][2] = __builtin_amdgcn_mfma_f32_16x16x32_bf16(wo1,         b0, z4, 0, 0, 0);
        }
#pragma unroll
        for (int kt = 1; kt < 8; ++kt) {
            const bf16x8 b   = hp[kt * 64];
            const bf16x8 wo0 = wobase[kt * 256];           // imm kt*4096
            const bf16x8 wo1 = wobase[kt * 256 + 16];      // imm kt*4096+256
            acc[0][0] = __builtin_amdgcn_mfma_f32_16x16x32_bf16(wA[kt][0][0], b, acc[0][0], 0, 0, 0);
            acc[0][1] = __builtin_amdgcn_mfma_f32_16x16x32_bf16(wA[kt][0][1], b, acc[0][1], 0, 0, 0);
            acc[0][2] = __builtin_amdgcn_mfma_f32_16x16x32_bf16(wo0,          b, acc[0][2], 0, 0, 0);
            acc[1][0] = __builtin_amdgcn_mfma_f32_16x16x32_bf16(wA[kt][1][0], b, acc[1][0], 0, 0, 0);
            acc[1][1] = __builtin_amdgcn_mfma_f32_16x16x32_bf16(wA[kt][1][1], b, acc[1][1], 0, 0, 0);
            acc[1][2] = __builtin_amdgcn_mfma_f32_16x16x32_bf16(wo1,          b, acc[1][2], 0, 0, 0);
        }

        // ---- 2-stage gate redistribution ----
        // stage A (xor 8): lanes m>=8 take ct=1 values for row m&7
        float zA[3][4];
#pragma unroll
        for (int q = 0; q < 4; ++q) {
#pragma unroll
            for (int g = 0; g < 3; ++g) {
                const float s = __shfl_xor(acc[1][g][q], 8);
                zA[g][q] = (m >= 8) ? s : acc[0][g][q];
            }
        }
        // stage B (xor 4): lanes with m&4 take partner's q={2,3} as their pair
        float z[3][2];
#pragma unroll
        for (int g = 0; g < 3; ++g) {
            const float u2 = __shfl_xor(zA[g][2], 4);
            const float u3 = __shfl_xor(zA[g][3], 4);
            z[g][0] = (m & 4) ? u2 : zA[g][0];
            z[g][1] = (m & 4) ? u3 : zA[g][1];
        }

        // ---- z += x @ Wx + b (VALU, fp32 coefs) ; gates; h-write ----
        unsigned short h2[2];
#pragma unroll
        for (int e = 0; e < 2; ++e) {
            const float zf = z[0][e] + cxw[e][0][3] + x0 * cxw[e][0][0] + x1 * cxw[e][0][1] + x2 * cxw[e][0][2];
            const float zg = z[1][e] + cxw[e][1][3] + x0 * cxw[e][1][0] + x1 * cxw[e][1][1] + x2 * cxw[e][1][2];
            const float zo = z[2][e] + cxw[e][2][3] + x0 * cxw[e][2][0] + x1 * cxw[e][2][1] + x2 * cxw[e][2][2];
            const float Ef = __builtin_amdgcn_exp2f(zf);
            const float Eg = __builtin_amdgcn_exp2f(zg);
            const float Eo = __builtin_amdgcn_exp2f(zo);
            const float u  = 1.0f + Eg;
            const float v  = 1.0f + Ef;
            const float t2 = iv[e] * (2.0f - u);          // i*(1-Eg)
            const float cq = (cst[e] * u + t2 * v) * __builtin_amdgcn_rcpf(u * v);
            cst[e] = cq;
            const float Ec = __builtin_amdgcn_exp2f(SF2 * cq);
            const float hq = (1.0f - Ec) * __builtin_amdgcn_rcpf((1.0f + Eo) * (1.0f + Ec));
            h2[e] = f2bf(hq);
        }
        {
            unsigned int pk = (unsigned)h2[0] | ((unsigned)h2[1] << 16);
            *(unsigned int*)&hw[woff] = pk;   // adjacent e-slots (kp&7 even)
        }
        __syncthreads();
    }

    // ---- head: out[r] = sum_c h[r][c] w_head[c] + b_head ----
    float p = 0.0f;
    {
        const unsigned short* hf = hbuf[1];   // t=364: cur=0, wrote hbuf[1]
        const unsigned int hv = *(const unsigned int*)&hf[woff];
        p = bf2f((unsigned short)(hv & 0xffff)) * w_head[cw0]
          + bf2f((unsigned short)(hv >> 16))    * w_head[cw0 + 1];
    }
    p += __shfl_xor(p, 4);    // combine q-pairs
    p += __shfl_xor(p, 8);    // combine ct halves
    p += __shfl_xor(p, 16);   // combine l16 groups
    p += __shfl_xor(p, 32);
    if (lane < ROWS) red[wv][lane] = p;
    __syncthreads();
    if (tid < ROWS) {
        float s = b_head[0];
#pragma unroll
        for (int w = 0; w < NW; ++w) s += red[w][tid];
        out[rb + tid] = s;
    }
}

extern "C" void kernel_launch(void* const* d_in, const int* in_sizes, int n_in,
                              void* d_out, int out_size, void* d_ws, size_t ws_size,
                              hipStream_t stream)
{
    const float* x_dyn  = (const float*)d_in[0];
    const float* x_stat = (const float*)d_in[1];
    const float* w_i    = (const float*)d_in[2];
    const float* b_i    = (const float*)d_in[3];
    const float* w_f    = (const float*)d_in[4];
    const float* b_f    = (const float*)d_in[5];
    const float* w_g    = (const float*)d_in[6];
    const float* b_g    = (const float*)d_in[7];
    const float* w_o    = (const float*)d_in[8];
    const float* b_o    = (const float*)d_in[9];
    const float* w_head = (const float*)d_in[10];
    const float* b_head = (const float*)d_in[11];

    ealstm_fused<<<dim3(NBLK), dim3(512), 0, stream>>>(
        x_dyn, x_stat, w_i, b_i, w_f, b_f, w_g, b_g, w_o, b_o,
        w_head, b_head, (float*)d_out);
}